// Round 12
// baseline (51.727 us; speedup 1.0000x reference)
//
#include <hip/hip_runtime.h>
#include <math.h>

#define Bsz 4096
#define Dk 128
#define RPB 32                   // rows per block
#define CS 16                    // column splits
#define CPB (Bsz / CS)           // 256 cols per block
#define THREADS 256
#define WAVES 4
#define CPW (CPB / WAVES)        // 64 cols per wave
#define CT (CPW / 16)            // 4 col-tiles per wave
#define RT (RPB / 16)            // 2 row-tiles
#define FXS 1099511627776.0      // 2^40 fixed-point scale

typedef __attribute__((ext_vector_type(8))) short short8;
typedef __attribute__((ext_vector_type(4))) float f32x4;

__device__ __forceinline__ unsigned short f2bf(float f) {
  unsigned u = __float_as_uint(f);
  u = (u + 0x7fffu + ((u >> 16) & 1u)) >> 16;   // RNE
  return (unsigned short)u;
}

// Xt layout: [kb][col][8], kb = k/8. Fragment loads = 4 x 256B contiguous
// segments per wave. Also zeroes the 33 atomic cells (accumulate across
// replays otherwise; ws is not re-poisoned).
__global__ __launch_bounds__(256)
void convert_kernel(const float* __restrict__ X, short* __restrict__ Xt,
                    unsigned long long* __restrict__ cells) {
  int i = blockIdx.x * 256 + threadIdx.x;     // 65536 = 4096 cols x 16 kb
  if (i < 33) cells[i] = 0ull;                // [0..15]=loss fx [16..31]=cnt [32]=done
  int col = i >> 4, kb = i & 15;
  const float4* q = (const float4*)(X + col * Dk + kb * 8);
  float4 v0 = q[0], v1 = q[1];
  short8 r;
  r[0] = (short)f2bf(v0.x); r[1] = (short)f2bf(v0.y);
  r[2] = (short)f2bf(v0.z); r[3] = (short)f2bf(v0.w);
  r[4] = (short)f2bf(v1.x); r[5] = (short)f2bf(v1.y);
  r[6] = (short)f2bf(v1.z); r[7] = (short)f2bf(v1.w);
  *(short8*)(Xt + (size_t)(kb * Bsz + col) * 8) = r;
}

__device__ __forceinline__ short8 ldfrag(const short* __restrict__ Xt, int col, int ks, int lg) {
  return *(const short8*)(Xt + (size_t)(((ks << 2) + lg) * Bsz + col) * 8);
}

// Single GEMM sweep: per row-slot accumulate 6 stats:
// min/max over positives (excl self), min/max over negatives,
// UNCONDITIONAL exp-sums Sp_all (pos, excl self) and Sn_all (neg).
__global__ __launch_bounds__(THREADS, 4)
void sweep6(const short* __restrict__ Xt, const int* __restrict__ labels,
            float* __restrict__ p_mnp, float* __restrict__ p_mxn,
            float* __restrict__ p_mxp, float* __restrict__ p_mnn,
            float* __restrict__ p_sp,  float* __restrict__ p_sn) {
  const int tid = threadIdx.x;
  const int w  = tid >> 6;
  const int l  = tid & 63;
  const int lg = l >> 4;
  const int lr = l & 15;
  const int by = blockIdx.x / CS;
  const int bx = blockIdx.x % CS;
  const int r0 = by * RPB;
  const int c0 = bx * CPB + w * CPW;

  __shared__ float red[6][WAVES][RPB];

  short8 afrag[RT][4];
  for (int rt = 0; rt < RT; ++rt)
    for (int ks = 0; ks < 4; ++ks)
      afrag[rt][ks] = ldfrag(Xt, r0 + rt * 16 + lr, ks, lg);

  int labr[RT * 4];
  for (int rt = 0; rt < RT; ++rt)
    for (int rg = 0; rg < 4; ++rg)
      labr[rt * 4 + rg] = labels[r0 + rt * 16 + lg * 4 + rg];

  float mnp[RT*4], mxn[RT*4], mxp[RT*4], mnn[RT*4], sp[RT*4], sn[RT*4];
  for (int i = 0; i < RT * 4; ++i) {
    mnp[i] = INFINITY; mxn[i] = -INFINITY;
    mxp[i] = -INFINITY; mnn[i] = INFINITY;
    sp[i] = 0.f; sn[i] = 0.f;
  }

#pragma unroll
  for (int ct = 0; ct < CT; ++ct) {
    const int ctc  = c0 + ct * 16;
    const int colv = ctc + lr;
    short8 bfrag[4];
    for (int ks = 0; ks < 4; ++ks) bfrag[ks] = ldfrag(Xt, colv, ks, lg);
    const int labc = labels[colv];

    for (int rt = 0; rt < RT; ++rt) {
      f32x4 acc = {0.f, 0.f, 0.f, 0.f};
      for (int ks = 0; ks < 4; ++ks)
        acc = __builtin_amdgcn_mfma_f32_16x16x32_bf16(afrag[rt][ks], bfrag[ks], acc, 0, 0, 0);
      const bool diag = (ctc == r0 + rt * 16);   // wave-uniform
      // C/D layout (verified): col = lane&15, row = (lane>>4)*4 + reg
      for (int rg = 0; rg < 4; ++rg) {
        int   i    = rt * 4 + rg;
        float s    = acc[rg];
        bool  eq   = (labc == labr[i]);
        bool  self = diag && (lr == lg * 4 + rg);
        bool  isp  = eq && !self;
        if (isp) { mnp[i] = fminf(mnp[i], s); mxp[i] = fmaxf(mxp[i], s); }
        if (!eq) { mxn[i] = fmaxf(mxn[i], s); mnn[i] = fminf(mnn[i], s); }
        float argp = fmaf(s, -2.885390082f, 1.442695041f);   // -2*(s-0.5)*log2e
        float argn = fmaf(s, 57.70780163f, -28.85390082f);   // 40*(s-0.5)*log2e
        float e = exp2f(isp ? argp : argn);
        sp[i] += isp ? e : 0.f;
        sn[i] += (!eq) ? e : 0.f;
      }
    }
  }

  // reduce across the 16 col-lanes sharing each row
  for (int i = 0; i < RT * 4; ++i) {
    for (int m = 1; m < 16; m <<= 1) {
      mnp[i] = fminf(mnp[i], __shfl_xor(mnp[i], m, 64));
      mxn[i] = fmaxf(mxn[i], __shfl_xor(mxn[i], m, 64));
      mxp[i] = fmaxf(mxp[i], __shfl_xor(mxp[i], m, 64));
      mnn[i] = fminf(mnn[i], __shfl_xor(mnn[i], m, 64));
      sp[i]  += __shfl_xor(sp[i], m, 64);
      sn[i]  += __shfl_xor(sn[i], m, 64);
    }
  }
  if (lr == 0)
    for (int i = 0; i < RT * 4; ++i) {
      int rt = i >> 2, rg = i & 3;
      int rl = rt * 16 + lg * 4 + rg;
      red[0][w][rl] = mnp[i]; red[1][w][rl] = mxn[i];
      red[2][w][rl] = mxp[i]; red[3][w][rl] = mnn[i];
      red[4][w][rl] = sp[i];  red[5][w][rl] = sn[i];
    }
  __syncthreads();

  if (tid < RPB) {
    float v0 = INFINITY, v1 = -INFINITY, v2 = -INFINITY, v3 = INFINITY, v4 = 0.f, v5 = 0.f;
    for (int ww = 0; ww < WAVES; ++ww) {
      v0 = fminf(v0, red[0][ww][tid]);
      v1 = fmaxf(v1, red[1][ww][tid]);
      v2 = fmaxf(v2, red[2][ww][tid]);
      v3 = fminf(v3, red[3][ww][tid]);
      v4 += red[4][ww][tid];
      v5 += red[5][ww][tid];
    }
    int o = bx * Bsz + r0 + tid;
    p_mnp[o] = v0; p_mxn[o] = v1; p_mxp[o] = v2; p_mnn[o] = v3;
    p_sp[o] = v4;  p_sn[o] = v5;
  }
}

// Correction: per (row-group, col-split). Check if any row's thresholds bind
// (pos exact-check; neg via rigorous tail bound). Early-exit when clean
// (expected). Dirty groups re-GEMM with exact thresholds.
__global__ __launch_bounds__(THREADS, 4)
void correct(const short* __restrict__ Xt, const int* __restrict__ labels,
             const float* __restrict__ p_mnp, const float* __restrict__ p_mxn,
             const float* __restrict__ p_mxp, const float* __restrict__ p_mnn,
             float* __restrict__ pos_part, float* __restrict__ neg_part,
             unsigned int* __restrict__ flags, float* __restrict__ vldA) {
  const int tid = threadIdx.x;
  const int by = blockIdx.x / CS;
  const int bx = blockIdx.x % CS;
  const int r0 = by * RPB;

  __shared__ float tp_s[RPB], tn_s[RPB];
  __shared__ int anyd;
  if (tid == 0) anyd = 0;

  // gather extremes: thread = row8*8 + spl, covers splits spl and spl+8
  const int row8 = tid >> 3, spl = tid & 7;
  const int r = r0 + row8;
  float mnp = fminf(p_mnp[spl * Bsz + r], p_mnp[(spl + 8) * Bsz + r]);
  float mxn = fmaxf(p_mxn[spl * Bsz + r], p_mxn[(spl + 8) * Bsz + r]);
  float mxp = fmaxf(p_mxp[spl * Bsz + r], p_mxp[(spl + 8) * Bsz + r]);
  float mnn = fminf(p_mnn[spl * Bsz + r], p_mnn[(spl + 8) * Bsz + r]);
  for (int m = 1; m < 8; m <<= 1) {
    mnp = fminf(mnp, __shfl_xor(mnp, m, 64));
    mxn = fmaxf(mxn, __shfl_xor(mxn, m, 64));
    mxp = fmaxf(mxp, __shfl_xor(mxp, m, 64));
    mnn = fminf(mnn, __shfl_xor(mnn, m, 64));
  }
  __syncthreads();   // anyd=0 visible
  if (spl == 0) {
    float tp = mxn + 0.1f, tn = mnp - 0.1f;
    tp_s[row8] = tp; tn_s[row8] = tn;
    bool posd = (mxp >= tp);                       // a positive would be excluded
    float bound = 4096.0f * exp2f(fmaf(tn, 57.70780163f, -28.85390082f));
    bool negd = (mnn <= tn) && (bound > 1e-7f);    // excluded-neg mass not negligible
    bool dirty = posd || negd;
    if (bx == 0) {
      flags[r] = dirty ? 1u : 0u;
      vldA[r]  = (tn < mxn) ? 1.f : 0.f;           // min_pos-0.1 < max_neg
    }
    if (dirty) atomicOr(&anyd, 1);
  }
  __syncthreads();
  if (!anyd) return;   // clean group: done (expected path)

  // ---- dirty: exact thresholded re-sweep for this (group, split) ----
  const int w  = tid >> 6;
  const int l  = tid & 63;
  const int lg = l >> 4;
  const int lr = l & 15;
  const int c0 = bx * CPB + w * CPW;

  __shared__ float red[2][WAVES][RPB];

  short8 afrag[RT][4];
  for (int rt = 0; rt < RT; ++rt)
    for (int ks = 0; ks < 4; ++ks)
      afrag[rt][ks] = ldfrag(Xt, r0 + rt * 16 + lr, ks, lg);
  int labr[RT * 4];
  float tp[RT * 4], tn[RT * 4];
  for (int rt = 0; rt < RT; ++rt)
    for (int rg = 0; rg < 4; ++rg) {
      int rl = rt * 16 + lg * 4 + rg;
      labr[rt * 4 + rg] = labels[r0 + rl];
      tp[rt * 4 + rg] = tp_s[rl];
      tn[rt * 4 + rg] = tn_s[rl];
    }

  float ap[RT * 4], an[RT * 4];
  for (int i = 0; i < RT * 4; ++i) { ap[i] = 0.f; an[i] = 0.f; }

#pragma unroll
  for (int ct = 0; ct < CT; ++ct) {
    const int ctc  = c0 + ct * 16;
    const int colv = ctc + lr;
    short8 bfrag[4];
    for (int ks = 0; ks < 4; ++ks) bfrag[ks] = ldfrag(Xt, colv, ks, lg);
    const int labc = labels[colv];
    for (int rt = 0; rt < RT; ++rt) {
      f32x4 acc = {0.f, 0.f, 0.f, 0.f};
      for (int ks = 0; ks < 4; ++ks)
        acc = __builtin_amdgcn_mfma_f32_16x16x32_bf16(afrag[rt][ks], bfrag[ks], acc, 0, 0, 0);
      const bool diag = (ctc == r0 + rt * 16);
      for (int rg = 0; rg < 4; ++rg) {
        int   i    = rt * 4 + rg;
        float s    = acc[rg];
        bool  eq   = (labc == labr[i]);
        bool  self = diag && (lr == lg * 4 + rg);
        bool  kp   = eq && !self && (s < tp[i]);
        bool  kn   = (!eq) && (s > tn[i]);
        float argp = fmaf(s, -2.885390082f, 1.442695041f);
        float argn = fmaf(s, 57.70780163f, -28.85390082f);
        float e = exp2f(kp ? argp : argn);
        ap[i] += kp ? e : 0.f;
        an[i] += kn ? e : 0.f;
      }
    }
  }
  for (int i = 0; i < RT * 4; ++i) {
    for (int m = 1; m < 16; m <<= 1) {
      ap[i] += __shfl_xor(ap[i], m, 64);
      an[i] += __shfl_xor(an[i], m, 64);
    }
  }
  if (lr == 0)
    for (int i = 0; i < RT * 4; ++i) {
      int rt = i >> 2, rg = i & 3;
      red[0][w][rt * 16 + lg * 4 + rg] = ap[i];
      red[1][w][rt * 16 + lg * 4 + rg] = an[i];
    }
  __syncthreads();
  if (tid < RPB) {
    float v0 = 0.f, v1 = 0.f;
    for (int ww = 0; ww < WAVES; ++ww) { v0 += red[0][ww][tid]; v1 += red[1][ww][tid]; }
    pos_part[bx * Bsz + r0 + tid] = v0;
    neg_part[bx * Bsz + r0 + tid] = v1;
  }
}

// Finalize: 16 blocks, one row per thread; exact fixed-point accumulation.
__global__ __launch_bounds__(256)
void finalize(const float* __restrict__ p_sp, const float* __restrict__ p_sn,
              const float* __restrict__ pos_part, const float* __restrict__ neg_part,
              const unsigned int* __restrict__ flags, const float* __restrict__ vldA,
              unsigned long long* __restrict__ cells, float* __restrict__ out) {
  const int tid = threadIdx.x;
  const int r = blockIdx.x * 256 + tid;
  float loss = 0.f, cnt = 0.f;
  {
    bool dirty = flags[r] != 0u;
    const float* Sp = dirty ? pos_part : p_sp;
    const float* Sn = dirty ? neg_part : p_sn;
    float P = 0.f, N = 0.f;
#pragma unroll
    for (int b = 0; b < CS; ++b) { P += Sp[b * Bsz + r]; N += Sn[b * Bsz + r]; }
    if (vldA[r] > 0.f) {
      loss = log1pf(P) * 0.5f + log1pf(N) * 0.025f;
      cnt  = 1.f;
    }
  }
  for (int m = 1; m < 64; m <<= 1) {
    loss += __shfl_xor(loss, m, 64);
    cnt  += __shfl_xor(cnt,  m, 64);
  }
  __shared__ float ls[4], cs[4];
  int w = tid >> 6, lz = tid & 63;
  if (lz == 0) { ls[w] = loss; cs[w] = cnt; }
  __syncthreads();
  if (tid == 0) {
    float L = 0.f, C = 0.f;
    for (int ww = 0; ww < 4; ++ww) { L += ls[ww]; C += cs[ww]; }
    atomicAdd(&cells[blockIdx.x & 15], (unsigned long long)(long long)((double)L * FXS));
    atomicAdd(&cells[16 + (blockIdx.x & 15)], (unsigned long long)(int)C);
    __threadfence();
    if (atomicAdd(&cells[32], 1ull) == (unsigned long long)(gridDim.x - 1)) {
      unsigned long long S = 0ull, C2 = 0ull;
      for (int i = 0; i < 16; ++i) {
        S  += atomicAdd(&cells[i], 0ull);
        C2 += atomicAdd(&cells[16 + i], 0ull);
      }
      out[0] = (float)((double)S / FXS / (double)(C2 ? C2 : 1ull));
    }
  }
}

extern "C" void kernel_launch(void* const* d_in, const int* in_sizes, int n_in,
                              void* d_out, int out_size, void* d_ws, size_t ws_size,
                              hipStream_t stream) {
  const float* X      = (const float*)d_in[0];
  const int*   labels = (const int*)d_in[1];

  char* ws = (char*)d_ws;
  short* Xt       = (short*)ws;                          // 1 MB
  float* p_mnp    = (float*)(ws + 1048576);              // 256 KB each (16 x 4096 f32)
  float* p_mxn    = (float*)(ws + 1048576 + 262144);
  float* p_mxp    = (float*)(ws + 1048576 + 524288);
  float* p_mnn    = (float*)(ws + 1048576 + 786432);
  float* p_sp     = (float*)(ws + 2097152);
  float* p_sn     = (float*)(ws + 2097152 + 262144);
  float* pos_part = (float*)(ws + 2097152 + 524288);
  float* neg_part = (float*)(ws + 2097152 + 786432);
  unsigned int* flags = (unsigned int*)(ws + 3145728);   // 16 KB
  float* vldA     = (float*)(ws + 3145728 + 16384);      // 16 KB
  unsigned long long* cells = (unsigned long long*)(ws + 3145728 + 32768);

  convert_kernel<<<256, 256, 0, stream>>>(X, Xt, cells);
  sweep6<<<(Bsz / RPB) * CS, THREADS, 0, stream>>>(Xt, labels, p_mnp, p_mxn, p_mxp, p_mnn, p_sp, p_sn);
  correct<<<(Bsz / RPB) * CS, THREADS, 0, stream>>>(Xt, labels, p_mnp, p_mxn, p_mxp, p_mnn,
                                                    pos_part, neg_part, flags, vldA);
  finalize<<<16, 256, 0, stream>>>(p_sp, p_sn, pos_part, neg_part, flags, vldA, cells, (float*)d_out);
}